// Round 13
// baseline (245.585 us; speedup 1.0000x reference)
//
#include <hip/hip_runtime.h>
#include <hip/hip_bf16.h>
#include <stdint.h>

// Problem constants: B=4, T=2048, C=1024, H=16, D=64. Inputs f32, output f32.
#define B_ 4
#define T_ 2048
#define C_ 1024
#define H_ 16
#define D_ 64

typedef __bf16 bf16;
typedef _Float16 f16;
typedef __attribute__((ext_vector_type(8))) __bf16 bf16x8;
typedef __attribute__((ext_vector_type(4))) __bf16 bf16x4;
typedef __attribute__((ext_vector_type(4))) _Float16 f16x4;
typedef __attribute__((ext_vector_type(8))) _Float16 f16x8;
typedef __attribute__((ext_vector_type(4))) float floatx4;

__device__ __forceinline__ floatx4 mfma16(bf16x8 a, bf16x8 b, floatx4 c) {
  return __builtin_amdgcn_mfma_f32_16x16x32_bf16(a, b, c, 0, 0, 0);
}
// full-rate f16 PV: 16x16x32 (gfx950 2xK shape), A/B = 8 f16 per lane
__device__ __forceinline__ floatx4 mfma_pv32(f16x8 a, f16x8 b, floatx4 c) {
  return __builtin_amdgcn_mfma_f32_16x16x32_f16(a, b, c, 0, 0, 0);
}

__device__ __forceinline__ void gl_lds16(const void* g, void* l) {
  __builtin_amdgcn_global_load_lds(
      (__attribute__((address_space(1))) uint32_t*)g,
      (__attribute__((address_space(3))) uint32_t*)l, 16, 0, 0);
}

// ---------------- fused preprocessing: cvt + both weight transposes --------
// blocks [0,8192):        x f32 -> xb bf16 (4 elem/thread)
// blocks [8192,11264):    w_qkv [1024,3072] -> wqkv_t [3072,1024] bf16
// blocks [11264,12288):   w_proj [1024,1024] -> wproj_t [1024,1024] bf16
__device__ __forceinline__ void tr_tile(const float* __restrict__ in,
                                        bf16* __restrict__ out, int K, int N,
                                        int n0, int k0, bf16 (*tile)[33]) {
  const int r = threadIdx.x >> 5, c = threadIdx.x & 31;
#pragma unroll
  for (int i = 0; i < 4; i++)
    tile[r + i * 8][c] = (bf16)in[(size_t)(k0 + r + i * 8) * N + n0 + c];
  __syncthreads();
#pragma unroll
  for (int i = 0; i < 4; i++)
    out[(size_t)(n0 + r + i * 8) * K + k0 + c] = tile[c][r + i * 8];
}

__global__ __launch_bounds__(256) void preproc(const float* __restrict__ x,
                                               bf16* __restrict__ xb,
                                               const float* __restrict__ w_qkv,
                                               bf16* __restrict__ wqkv_t,
                                               const float* __restrict__ w_proj,
                                               bf16* __restrict__ wproj_t) {
  __shared__ bf16 tile[32][33];
  const int bid = blockIdx.x;
  if (bid < 8192) {
    const size_t i = ((size_t)bid * 256 + threadIdx.x) * 4;
    const floatx4 v = *(const floatx4*)(x + i);
    bf16x4 r;
#pragma unroll
    for (int j = 0; j < 4; j++) r[j] = (bf16)v[j];
    *(bf16x4*)(xb + i) = r;
  } else if (bid < 11264) {
    const int rem = bid - 8192;  // 96 x 32
    tr_tile(w_qkv, wqkv_t, 1024, 3072, (rem % 96) * 32, (rem / 96) * 32, tile);
  } else {
    const int rem = bid - 11264;  // 32 x 32
    tr_tile(w_proj, wproj_t, 1024, 1024, (rem % 32) * 32, (rem / 32) * 32, tile);
  }
}

// ---------------- 128x128 bf16 MFMA GEMM, BK=64 (two half-buffers) ----------
// C[M,N] = A[M,K] @ Bt[N,K]^T
// MODE 0 (QKV, SWAPPED orientation): A=wqkv_t rows=channels (M=3072),
//   Bt=xb rows=tokens (N=8192), bias indexed by CHANNEL (row).
//   Kp: [bh][kt(64)][st(2)][half(2)][lane(64)][8 bf16]
//   Vp: [bh][kt(64)][sub(4)][lane(64)][8 f16]
// MODE 1 (proj): A=yb rows=tokens, bias by column, f32 row-major out.
// T1: XCD-chunked blockIdx swizzle (both grids % 8 == 0 -> bijective).
// T2 (this round): both-sides LDS chunk swizzle. The [128][32]-bf16 tile's
// ds_read_b128 at (row*64 + quad*16) is an 8-way bank conflict (8 even-col
// lanes share one 4-bank run -> SQ_LDS_BANK_CONFLICT 6.29M/dispatch). Fix:
// LDS slot (row, s) holds K-chunk s ^ ((row>>1)&3) -- applied by
// PRE-SWIZZLING the global source (gl_lds dest stays linear, m104 rule) and
// XOR-ing the read slot. After: each 4-bank run shared by exactly 2 lanes
// (cols differing by 8) = free (m136). Sync structure untouched.
template <int MODE>
__global__ __launch_bounds__(256) void gemm128(const bf16* __restrict__ A,
                                               const bf16* __restrict__ Bt,
                                               const float* __restrict__ bias,
                                               void* __restrict__ o0,
                                               bf16* __restrict__ o1,
                                               f16* __restrict__ o2,
                                               int M, int N, int K) {
  __shared__ __align__(16) bf16 As[2][128 * 32];
  __shared__ __align__(16) bf16 Bs[2][128 * 32];
  const int tid = threadIdx.x;

  int bx, by;
  if (MODE == 0) {
    // grid (64, 24): 1536 blocks, flat id = x + y*64
    const int id = blockIdx.x + blockIdx.y * 64;
    const int xcd = id & 7, r = id >> 3;  // r in [0,192)
    bx = xcd * 8 + (r & 7);               // token-panel, [0,64)
    by = r >> 3;                          // channel-panel, [0,24)
  } else {
    // grid (8, 64): 512 blocks, flat id = x + y*8
    const int id = blockIdx.x + blockIdx.y * 8;
    const int xcd = id & 7, r = id >> 3;  // r in [0,64)
    bx = r & 7;                           // col-panel, [0,8)
    by = xcd * 8 + (r >> 3);              // row-panel, [0,64)
  }
  const int m0 = by * 128, n0 = bx * 128;

  const int lane = tid & 63, wv = tid >> 6;
  const int wm = (wv >> 1) * 64, wn = (wv & 1) * 64;
  const int col = lane & 15, quad = lane >> 4;

  floatx4 acc[4][4];
#pragma unroll
  for (int i = 0; i < 4; i++)
#pragma unroll
    for (int j = 0; j < 4; j++) acc[i][j] = (floatx4){0.f, 0.f, 0.f, 0.f};

  // staging: thread stages LDS slot (row = c>>2, s = c&3); pre-swizzled
  // global source chunk = s ^ ((row>>1)&3)  [row>>1 == c>>3]
  const int c0 = tid, c1 = tid + 256;
  const int sw0 = ((c0 & 3) ^ ((c0 >> 3) & 3)) * 8;
  const int sw1 = ((c1 & 3) ^ ((c1 >> 3) & 3)) * 8;
  const bf16* a0 = A + (size_t)(m0 + (c0 >> 2)) * K + sw0;
  const bf16* a1 = A + (size_t)(m0 + (c1 >> 2)) * K + sw1;
  const bf16* b0 = Bt + (size_t)(n0 + (c0 >> 2)) * K + sw0;
  const bf16* b1 = Bt + (size_t)(n0 + (c1 >> 2)) * K + sw1;

  // read: desired K-chunk quad lives at slot quad ^ ((row>>1)&3); fragment
  // rows are wm/wn + mb*16 + col (16-aligned bases) -> f = (col>>1)&3
  const int rq = (quad ^ ((col >> 1) & 3)) * 8;

  for (int kt = 0; kt < K; kt += 64) {
#pragma unroll
    for (int hf = 0; hf < 2; hf++) {
      const int ko = kt + hf * 32;
      gl_lds16(a0 + ko, &As[hf][(wv * 64) * 8]);
      gl_lds16(a1 + ko, &As[hf][(wv * 64 + 256) * 8]);
      gl_lds16(b0 + ko, &Bs[hf][(wv * 64) * 8]);
      gl_lds16(b1 + ko, &Bs[hf][(wv * 64 + 256) * 8]);
    }
    __syncthreads();
#pragma unroll
    for (int hf = 0; hf < 2; hf++) {
      bf16x8 afr[4], bg[4];
#pragma unroll
      for (int mb = 0; mb < 4; mb++)
        afr[mb] = *(const bf16x8*)&As[hf][(wm + mb * 16 + col) * 32 + rq];
#pragma unroll
      for (int nb = 0; nb < 4; nb++)
        bg[nb] = *(const bf16x8*)&Bs[hf][(wn + nb * 16 + col) * 32 + rq];
#pragma unroll
      for (int mb = 0; mb < 4; mb++)
#pragma unroll
        for (int nb = 0; nb < 4; nb++)
          acc[mb][nb] = mfma16(afr[mb], bg[nb], acc[mb][nb]);
    }
    __syncthreads();
  }

#pragma unroll
  for (int mb = 0; mb < 4; mb++) {
    const int mgq = m0 + wm + mb * 16 + quad * 4;  // 4 consecutive rows
    if (MODE == 0) {
      // rows are channels; third/h/d block-uniform-ish, d0 4-aligned
      const int third = mgq >> 10;
      const int nn0 = mgq & 1023;
      const int h = nn0 >> 6, d0 = nn0 & 63;
      float bs[4];
#pragma unroll
      for (int r = 0; r < 4; r++) bs[r] = bias[mgq + r];
#pragma unroll
      for (int nb = 0; nb < 4; nb++) {
        const int t = n0 + wn + nb * 16 + col;  // token
        const int bb = t >> 11, tt = t & 2047;
        const size_t bh = (size_t)bb * H_ + h;
        float v[4];
#pragma unroll
        for (int r = 0; r < 4; r++) v[r] = acc[mb][nb][r] + bs[r];
        if (third == 0) {
          bf16x4 y;
#pragma unroll
          for (int r = 0; r < 4; r++) y[r] = (bf16)v[r];
          *(bf16x4*)&((bf16*)o0)[(bh * T_ + tt) * D_ + d0] = y;
        } else if (third == 1) {
          const int lane2 = (tt & 15) | (((d0 >> 3) & 3) << 4);
          const size_t idx =
              ((((bh * 64 + (tt >> 5)) * 2 + ((tt >> 4) & 1)) * 2 + (d0 >> 5)) * 64 +
               lane2) * 8 + (d0 & 7);
          bf16x4 y;
#pragma unroll
          for (int r = 0; r < 4; r++) y[r] = (bf16)v[r];
          *(bf16x4*)&o1[idx] = y;
        } else {
#pragma unroll
          for (int r = 0; r < 4; r++) {
            const int d = d0 + r;
            const int lane2 = (d & 15) | (((tt >> 2) & 3) << 4);
            const size_t idx =
                (((bh * 64 + (tt >> 5)) * 4 + (d >> 4)) * 64 + lane2) * 8 +
                ((tt >> 4) & 1) * 4 + (tt & 3);
            o2[idx] = (f16)v[r];
          }
        }
      }
    } else {
#pragma unroll
      for (int nb = 0; nb < 4; nb++) {
        const int ng = n0 + wn + nb * 16 + col;
        const float bsc = bias[ng];
#pragma unroll
        for (int r = 0; r < 4; r++)
          ((float*)o0)[(size_t)(mgq + r) * N + ng] = acc[mb][nb][r] + bsc;
      }
    }
  }
}

// ---------------- flash attention: 4-wave block shares K/V via LDS ----------
// r10 version verbatim (proven best attn). Block = 4 waves, same bh,
// consecutive 32-row q-tiles. Each K/V tile (4KB K + 4KB V, contiguous in
// fragment-major layout) staged to LDS once per block, consumed by all 4
// waves. 2-phase: stage(t+1) issues before compute(t); one barrier per tile.
__global__ __launch_bounds__(256, 4) void attn(const bf16* __restrict__ Q,
                                               const bf16* __restrict__ Kp,
                                               const f16* __restrict__ Vp,
                                               bf16* __restrict__ Y) {
  __shared__ __align__(16) char kv[2][8192];  // [buf][K 4KB | V 4KB]
  const int tid = threadIdx.x, lane = tid & 63, wv = tid >> 6;
  const int col = lane & 15, quad = lane >> 4;
  const int id = blockIdx.x;  // [0, 1024)
  const int j = id >> 3;      // [0, 128)
  const int bh = ((j & 7) << 3) | (id & 7);
  const int qg = 15 - (j >> 3);  // q-group (128 rows); longest first
  const int b = bh >> 4, h = bh & 15;
  const int myqt = qg * 4 + wv;   // this wave's 32-row q-tile
  const int qbase = myqt * 32;
  const int ktb = qg * 4 + 3;     // block's last key tile

  bf16x8 qf[2][2];
#pragma unroll
  for (int mq = 0; mq < 2; mq++) {
    const bf16* qp = Q + ((size_t)bh * T_ + qbase + mq * 16 + col) * D_ + quad * 8;
    qf[mq][0] = *(const bf16x8*)qp;
    qf[mq][1] = *(const bf16x8*)(qp + 32);
  }

  floatx4 o[2][4];  // O^T: dim = sub*16 + quad*4 + r, qrow = col
  float lsum[2] = {0.f, 0.f};
#pragma unroll
  for (int mq = 0; mq < 2; mq++)
#pragma unroll
    for (int s = 0; s < 4; s++) o[mq][s] = (floatx4){0.f, 0.f, 0.f, 0.f};

  const float C1 = 0.18033688f;  // 0.125*log2(e)
  const float C2 = 11.541560f;   // 8*log2(e): p = exp2(s*C1 - C2), exact softmax

  const bf16* kroot = Kp + (size_t)bh * 64 * 2048;
  const f16* vroot = Vp + (size_t)bh * 64 * 2048;

  // wave wv stages 2KB: chunks u = wv*2, wv*2+1 (u<4: K, u>=4: V)
  auto stage = [&](int kt, int bufi) {
    const int u = wv * 2;
    if (wv < 2) {
      const bf16* kb = kroot + (size_t)kt * 2048 + lane * 8;
      gl_lds16(kb + u * 512, &kv[bufi][u * 1024]);
      gl_lds16(kb + (u + 1) * 512, &kv[bufi][(u + 1) * 1024]);
    } else {
      const f16* vb = vroot + (size_t)kt * 2048 + lane * 8;
      gl_lds16(vb + (u - 4) * 512, &kv[bufi][u * 1024]);
      gl_lds16(vb + (u - 3) * 512, &kv[bufi][(u + 1) * 1024]);
    }
  };

  int buf = 0;
  stage(0, 0);
  __syncthreads();  // drains vmcnt: tile 0 landed

  for (int kt = 0; kt <= ktb; ++kt) {
    if (kt + 1 <= ktb) stage(kt + 1, buf ^ 1);
    if (kt <= myqt) {
      bf16x8 ka[2][2];
#pragma unroll
      for (int st = 0; st < 2; st++)
#pragma unroll
        for (int hf = 0; hf < 2; hf++)
          ka[st][hf] = *(const bf16x8*)&kv[buf][(st * 2 + hf) * 1024 + lane * 16];
      f16x8 vvr[4];
#pragma unroll
      for (int sub = 0; sub < 4; sub++)
        vvr[sub] = *(const f16x8*)&kv[buf][4096 + sub * 1024 + lane * 16];

      const bool masked = (kt == myqt);
      __builtin_amdgcn_s_setprio(1);
      f16x8 pf8[2];
#pragma unroll
      for (int mq = 0; mq < 2; mq++) pf8[mq] = (f16x8){};
#pragma unroll
      for (int st = 0; st < 2; st++) {
#pragma unroll
        for (int mq = 0; mq < 2; mq++) {
          if (masked && mq == 0 && st == 1) continue;  // fully masked sub-tile
          floatx4 s = (floatx4){0.f, 0.f, 0.f, 0.f};
          s = mfma16(ka[st][0], qf[mq][0], s);
          s = mfma16(ka[st][1], qf[mq][1], s);
          float ps = 0.f;
          const bool diag = masked && (mq == st);
#pragma unroll
          for (int r = 0; r < 4; r++) {
            float p = __builtin_amdgcn_exp2f(fmaf(s[r], C1, -C2));
            if (diag && (quad * 4 + r > col)) p = 0.f;
            ps += p;
            pf8[mq][st * 4 + r] = (f16)p;
          }
          lsum[mq] += ps;
        }
      }
#pragma unroll
      for (int mq = 0; mq < 2; mq++)
#pragma unroll
        for (int sub = 0; sub < 4; sub++)
          o[mq][sub] = mfma_pv32(vvr[sub], pf8[mq], o[mq][sub]);
      __builtin_amdgcn_s_setprio(0);
    }
    __syncthreads();  // all waves done reading kv[buf]; stage(kt+1) landed
    buf ^= 1;
  }

#pragma unroll
  for (int mq = 0; mq < 2; mq++) {
    lsum[mq] += __shfl_xor(lsum[mq], 16);
    lsum[mq] += __shfl_xor(lsum[mq], 32);
    const float rinv = 1.f / lsum[mq];
    const int qrow = qbase + mq * 16 + col;
#pragma unroll
    for (int sub = 0; sub < 4; sub++) {
      bf16x4 yv;
#pragma unroll
      for (int r = 0; r < 4; r++) yv[r] = (bf16)(o[mq][sub][r] * rinv);
      *(bf16x4*)&Y[((size_t)b * T_ + qrow) * C_ + h * 64 + sub * 16 + quad * 4] = yv;
    }
  }
}

extern "C" void kernel_launch(void* const* d_in, const int* in_sizes, int n_in,
                              void* d_out, int out_size, void* d_ws, size_t ws_size,
                              hipStream_t stream) {
  (void)in_sizes; (void)n_in; (void)out_size; (void)ws_size;
  const float* x      = (const float*)d_in[0];  // [B*T, C]
  const float* w_qkv  = (const float*)d_in[1];  // [C, 3C]
  const float* b_qkv  = (const float*)d_in[2];  // [3C]
  const float* w_proj = (const float*)d_in[3];  // [C, C]
  const float* b_proj = (const float*)d_in[4];  // [C]

  char* ws = (char*)d_ws;
  bf16* wqkv_t  = (bf16*)(ws);                  // [3C, C]   6291456 B
  bf16* wproj_t = (bf16*)(ws + 6291456);        // [C, C]    2097152 B
  bf16* qb      = (bf16*)(ws + 8388608);        // [B,H,T,D] 16777216 B
  bf16* kbuf    = (bf16*)(ws + 25165824);       // K frag-major 16777216 B
  f16*  vtbuf   = (f16*)(ws + 41943040);        // V frag-major 16777216 B
  bf16* yb      = (bf16*)(ws + 58720256);       // [B*T, C]  16777216 B
  bf16* xb      = (bf16*)(ws + 58720256);       // aliases yb (dead before attn)

  preproc<<<12288, 256, 0, stream>>>(x, xb, w_qkv, wqkv_t, w_proj, wproj_t);
  // SWAPPED: A = wqkv_t (channels), Bt = xb (tokens)
  gemm128<0><<<dim3(64, 24), 256, 0, stream>>>(wqkv_t, xb, b_qkv, qb, kbuf, vtbuf,
                                               3072, 8192, 1024);
  attn<<<dim3(1024), 256, 0, stream>>>(qb, kbuf, vtbuf, yb);
  gemm128<1><<<dim3(8, 64), 256, 0, stream>>>(yb, wproj_t, b_proj, d_out, nullptr,
                                              nullptr, 8192, 1024, 1024);
}

// Round 14
// 236.996 us; speedup vs baseline: 1.0362x; 1.0362x over previous
//
#include <hip/hip_runtime.h>
#include <hip/hip_bf16.h>
#include <stdint.h>

// Problem constants: B=4, T=2048, C=1024, H=16, D=64. Inputs f32, output f32.
#define B_ 4
#define T_ 2048
#define C_ 1024
#define H_ 16
#define D_ 64

typedef __bf16 bf16;
typedef _Float16 f16;
typedef __attribute__((ext_vector_type(8))) __bf16 bf16x8;
typedef __attribute__((ext_vector_type(4))) __bf16 bf16x4;
typedef __attribute__((ext_vector_type(4))) _Float16 f16x4;
typedef __attribute__((ext_vector_type(8))) _Float16 f16x8;
typedef __attribute__((ext_vector_type(4))) float floatx4;

__device__ __forceinline__ floatx4 mfma16(bf16x8 a, bf16x8 b, floatx4 c) {
  return __builtin_amdgcn_mfma_f32_16x16x32_bf16(a, b, c, 0, 0, 0);
}
// full-rate f16 PV: 16x16x32 (gfx950 2xK shape), A/B = 8 f16 per lane
__device__ __forceinline__ floatx4 mfma_pv32(f16x8 a, f16x8 b, floatx4 c) {
  return __builtin_amdgcn_mfma_f32_16x16x32_f16(a, b, c, 0, 0, 0);
}

__device__ __forceinline__ void gl_lds16(const void* g, void* l) {
  __builtin_amdgcn_global_load_lds(
      (__attribute__((address_space(1))) uint32_t*)g,
      (__attribute__((address_space(3))) uint32_t*)l, 16, 0, 0);
}

// ---------------- fused preprocessing: cvt + both weight transposes --------
// blocks [0,8192):        x f32 -> xb bf16 (4 elem/thread)
// blocks [8192,11264):    w_qkv [1024,3072] -> wqkv_t [3072,1024] bf16
// blocks [11264,12288):   w_proj [1024,1024] -> wproj_t [1024,1024] bf16
__device__ __forceinline__ void tr_tile(const float* __restrict__ in,
                                        bf16* __restrict__ out, int K, int N,
                                        int n0, int k0, bf16 (*tile)[33]) {
  const int r = threadIdx.x >> 5, c = threadIdx.x & 31;
#pragma unroll
  for (int i = 0; i < 4; i++)
    tile[r + i * 8][c] = (bf16)in[(size_t)(k0 + r + i * 8) * N + n0 + c];
  __syncthreads();
#pragma unroll
  for (int i = 0; i < 4; i++)
    out[(size_t)(n0 + r + i * 8) * K + k0 + c] = tile[c][r + i * 8];
}

__global__ __launch_bounds__(256) void preproc(const float* __restrict__ x,
                                               bf16* __restrict__ xb,
                                               const float* __restrict__ w_qkv,
                                               bf16* __restrict__ wqkv_t,
                                               const float* __restrict__ w_proj,
                                               bf16* __restrict__ wproj_t) {
  __shared__ bf16 tile[32][33];
  const int bid = blockIdx.x;
  if (bid < 8192) {
    const size_t i = ((size_t)bid * 256 + threadIdx.x) * 4;
    const floatx4 v = *(const floatx4*)(x + i);
    bf16x4 r;
#pragma unroll
    for (int j = 0; j < 4; j++) r[j] = (bf16)v[j];
    *(bf16x4*)(xb + i) = r;
  } else if (bid < 11264) {
    const int rem = bid - 8192;  // 96 x 32
    tr_tile(w_qkv, wqkv_t, 1024, 3072, (rem % 96) * 32, (rem / 96) * 32, tile);
  } else {
    const int rem = bid - 11264;  // 32 x 32
    tr_tile(w_proj, wproj_t, 1024, 1024, (rem % 32) * 32, (rem / 32) * 32, tile);
  }
}

// ---------------- 128x128 bf16 MFMA GEMM, BK=64 (two half-buffers) ----------
// C[M,N] = A[M,K] @ Bt[N,K]^T
// MODE 0 (QKV, SWAPPED orientation): A=wqkv_t rows=channels (M=3072),
//   Bt=xb rows=tokens (N=8192), bias indexed by CHANNEL (row).
//   Whole blocks map to one third (Q/K/V) -> uniform epilogue, packed stores.
//   Kp: [bh][kt(64)][st(2)][half(2)][lane(64)][8 bf16]
//   Vp: [bh][kt(64)][sub(4)][lane(64)][8 f16]  (elem j = st*4 + (tt&3) ->
//       exactly the 16x16x32 f16 A-fragment k-mapping k32 = quad*8 + j)
// MODE 1 (proj): A=yb rows=tokens, bias by column, f32 row-major out.
// T1: XCD-chunked blockIdx swizzle (both grids % 8 == 0 -> bijective).
// NOTE: LDS bank conflicts (6.29M/dispatch) are MEASURED-MASKED here: the
// T2 both-sides swizzle zeroed the counter with no timing change (r13),
// confirming the 2-phase critical path hides the LDS-read pipe (m252).
template <int MODE>
__global__ __launch_bounds__(256) void gemm128(const bf16* __restrict__ A,
                                               const bf16* __restrict__ Bt,
                                               const float* __restrict__ bias,
                                               void* __restrict__ o0,
                                               bf16* __restrict__ o1,
                                               f16* __restrict__ o2,
                                               int M, int N, int K) {
  __shared__ __align__(16) bf16 As[2][128 * 32];
  __shared__ __align__(16) bf16 Bs[2][128 * 32];
  const int tid = threadIdx.x;

  int bx, by;
  if (MODE == 0) {
    // grid (64, 24): 1536 blocks, flat id = x + y*64
    const int id = blockIdx.x + blockIdx.y * 64;
    const int xcd = id & 7, r = id >> 3;  // r in [0,192)
    bx = xcd * 8 + (r & 7);               // token-panel, [0,64)
    by = r >> 3;                          // channel-panel, [0,24)
  } else {
    // grid (8, 64): 512 blocks, flat id = x + y*8
    const int id = blockIdx.x + blockIdx.y * 8;
    const int xcd = id & 7, r = id >> 3;  // r in [0,64)
    bx = r & 7;                           // col-panel, [0,8)
    by = xcd * 8 + (r >> 3);              // row-panel, [0,64)
  }
  const int m0 = by * 128, n0 = bx * 128;

  const int lane = tid & 63, wv = tid >> 6;
  const int wm = (wv >> 1) * 64, wn = (wv & 1) * 64;
  const int col = lane & 15, quad = lane >> 4;

  floatx4 acc[4][4];
#pragma unroll
  for (int i = 0; i < 4; i++)
#pragma unroll
    for (int j = 0; j < 4; j++) acc[i][j] = (floatx4){0.f, 0.f, 0.f, 0.f};

  const int c0 = tid, c1 = tid + 256;
  const bf16* a0 = A + (size_t)(m0 + (c0 >> 2)) * K + (c0 & 3) * 8;
  const bf16* a1 = A + (size_t)(m0 + (c1 >> 2)) * K + (c1 & 3) * 8;
  const bf16* b0 = Bt + (size_t)(n0 + (c0 >> 2)) * K + (c0 & 3) * 8;
  const bf16* b1 = Bt + (size_t)(n0 + (c1 >> 2)) * K + (c1 & 3) * 8;

  for (int kt = 0; kt < K; kt += 64) {
#pragma unroll
    for (int hf = 0; hf < 2; hf++) {
      const int ko = kt + hf * 32;
      gl_lds16(a0 + ko, &As[hf][(wv * 64) * 8]);
      gl_lds16(a1 + ko, &As[hf][(wv * 64 + 256) * 8]);
      gl_lds16(b0 + ko, &Bs[hf][(wv * 64) * 8]);
      gl_lds16(b1 + ko, &Bs[hf][(wv * 64 + 256) * 8]);
    }
    __syncthreads();
#pragma unroll
    for (int hf = 0; hf < 2; hf++) {
      bf16x8 afr[4], bg[4];
#pragma unroll
      for (int mb = 0; mb < 4; mb++)
        afr[mb] = *(const bf16x8*)&As[hf][(wm + mb * 16 + col) * 32 + quad * 8];
#pragma unroll
      for (int nb = 0; nb < 4; nb++)
        bg[nb] = *(const bf16x8*)&Bs[hf][(wn + nb * 16 + col) * 32 + quad * 8];
#pragma unroll
      for (int mb = 0; mb < 4; mb++)
#pragma unroll
        for (int nb = 0; nb < 4; nb++)
          acc[mb][nb] = mfma16(afr[mb], bg[nb], acc[mb][nb]);
    }
    __syncthreads();
  }

#pragma unroll
  for (int mb = 0; mb < 4; mb++) {
    const int mgq = m0 + wm + mb * 16 + quad * 4;  // 4 consecutive rows
    if (MODE == 0) {
      // rows are channels; third/h/d block-uniform-ish, d0 4-aligned
      const int third = mgq >> 10;
      const int nn0 = mgq & 1023;
      const int h = nn0 >> 6, d0 = nn0 & 63;
      float bs[4];
#pragma unroll
      for (int r = 0; r < 4; r++) bs[r] = bias[mgq + r];
#pragma unroll
      for (int nb = 0; nb < 4; nb++) {
        const int t = n0 + wn + nb * 16 + col;  // token
        const int bb = t >> 11, tt = t & 2047;
        const size_t bh = (size_t)bb * H_ + h;
        float v[4];
#pragma unroll
        for (int r = 0; r < 4; r++) v[r] = acc[mb][nb][r] + bs[r];
        if (third == 0) {
          bf16x4 y;
#pragma unroll
          for (int r = 0; r < 4; r++) y[r] = (bf16)v[r];
          *(bf16x4*)&((bf16*)o0)[(bh * T_ + tt) * D_ + d0] = y;
        } else if (third == 1) {
          const int lane2 = (tt & 15) | (((d0 >> 3) & 3) << 4);
          const size_t idx =
              ((((bh * 64 + (tt >> 5)) * 2 + ((tt >> 4) & 1)) * 2 + (d0 >> 5)) * 64 +
               lane2) * 8 + (d0 & 7);
          bf16x4 y;
#pragma unroll
          for (int r = 0; r < 4; r++) y[r] = (bf16)v[r];
          *(bf16x4*)&o1[idx] = y;
        } else {
#pragma unroll
          for (int r = 0; r < 4; r++) {
            const int d = d0 + r;
            const int lane2 = (d & 15) | (((tt >> 2) & 3) << 4);
            const size_t idx =
                (((bh * 64 + (tt >> 5)) * 4 + (d >> 4)) * 64 + lane2) * 8 +
                ((tt >> 4) & 1) * 4 + (tt & 3);
            o2[idx] = (f16)v[r];
          }
        }
      }
    } else {
#pragma unroll
      for (int nb = 0; nb < 4; nb++) {
        const int ng = n0 + wn + nb * 16 + col;
        const float bsc = bias[ng];
#pragma unroll
        for (int r = 0; r < 4; r++)
          ((float*)o0)[(size_t)(mgq + r) * N + ng] = acc[mb][nb][r] + bsc;
      }
    }
  }
}

// ---------------- flash attention: 4-wave block shares K/V via LDS ----------
// r10 version verbatim (proven best attn, session-best total 237.7us).
// Block = 4 waves, same bh, consecutive 32-row q-tiles. Each K/V tile
// (4KB K + 4KB V, contiguous in fragment-major layout) staged to LDS once
// per block, consumed by all 4 waves -> K/V L2 traffic /4. 2-phase:
// stage(t+1) issues before compute(t); one barrier per tile is the fence.
// Refinements measured-refuted: V-from-L2 pipe-split (r11, +17us),
// pair-unroll/fewer barriers (r12, +3us) -> this is the structural floor.
__global__ __launch_bounds__(256, 4) void attn(const bf16* __restrict__ Q,
                                               const bf16* __restrict__ Kp,
                                               const f16* __restrict__ Vp,
                                               bf16* __restrict__ Y) {
  __shared__ __align__(16) char kv[2][8192];  // [buf][K 4KB | V 4KB]
  const int tid = threadIdx.x, lane = tid & 63, wv = tid >> 6;
  const int col = lane & 15, quad = lane >> 4;
  const int id = blockIdx.x;  // [0, 1024)
  const int j = id >> 3;      // [0, 128)
  const int bh = ((j & 7) << 3) | (id & 7);
  const int qg = 15 - (j >> 3);  // q-group (128 rows); longest first
  const int b = bh >> 4, h = bh & 15;
  const int myqt = qg * 4 + wv;   // this wave's 32-row q-tile
  const int qbase = myqt * 32;
  const int ktb = qg * 4 + 3;     // block's last key tile

  bf16x8 qf[2][2];
#pragma unroll
  for (int mq = 0; mq < 2; mq++) {
    const bf16* qp = Q + ((size_t)bh * T_ + qbase + mq * 16 + col) * D_ + quad * 8;
    qf[mq][0] = *(const bf16x8*)qp;
    qf[mq][1] = *(const bf16x8*)(qp + 32);
  }

  floatx4 o[2][4];  // O^T: dim = sub*16 + quad*4 + r, qrow = col
  float lsum[2] = {0.f, 0.f};
#pragma unroll
  for (int mq = 0; mq < 2; mq++)
#pragma unroll
    for (int s = 0; s < 4; s++) o[mq][s] = (floatx4){0.f, 0.f, 0.f, 0.f};

  const float C1 = 0.18033688f;  // 0.125*log2(e)
  const float C2 = 11.541560f;   // 8*log2(e): p = exp2(s*C1 - C2), exact softmax

  const bf16* kroot = Kp + (size_t)bh * 64 * 2048;
  const f16* vroot = Vp + (size_t)bh * 64 * 2048;

  // wave wv stages 2KB: chunks u = wv*2, wv*2+1 (u<4: K, u>=4: V)
  auto stage = [&](int kt, int bufi) {
    const int u = wv * 2;
    if (wv < 2) {
      const bf16* kb = kroot + (size_t)kt * 2048 + lane * 8;
      gl_lds16(kb + u * 512, &kv[bufi][u * 1024]);
      gl_lds16(kb + (u + 1) * 512, &kv[bufi][(u + 1) * 1024]);
    } else {
      const f16* vb = vroot + (size_t)kt * 2048 + lane * 8;
      gl_lds16(vb + (u - 4) * 512, &kv[bufi][u * 1024]);
      gl_lds16(vb + (u - 3) * 512, &kv[bufi][(u + 1) * 1024]);
    }
  };

  int buf = 0;
  stage(0, 0);
  __syncthreads();  // drains vmcnt: tile 0 landed

  for (int kt = 0; kt <= ktb; ++kt) {
    if (kt + 1 <= ktb) stage(kt + 1, buf ^ 1);
    if (kt <= myqt) {
      bf16x8 ka[2][2];
#pragma unroll
      for (int st = 0; st < 2; st++)
#pragma unroll
        for (int hf = 0; hf < 2; hf++)
          ka[st][hf] = *(const bf16x8*)&kv[buf][(st * 2 + hf) * 1024 + lane * 16];
      f16x8 vvr[4];
#pragma unroll
      for (int sub = 0; sub < 4; sub++)
        vvr[sub] = *(const f16x8*)&kv[buf][4096 + sub * 1024 + lane * 16];

      const bool masked = (kt == myqt);
      __builtin_amdgcn_s_setprio(1);
      f16x8 pf8[2];
#pragma unroll
      for (int mq = 0; mq < 2; mq++) pf8[mq] = (f16x8){};
#pragma unroll
      for (int st = 0; st < 2; st++) {
#pragma unroll
        for (int mq = 0; mq < 2; mq++) {
          if (masked && mq == 0 && st == 1) continue;  // fully masked sub-tile
          floatx4 s = (floatx4){0.f, 0.f, 0.f, 0.f};
          s = mfma16(ka[st][0], qf[mq][0], s);
          s = mfma16(ka[st][1], qf[mq][1], s);
          float ps = 0.f;
          const bool diag = masked && (mq == st);
#pragma unroll
          for (int r = 0; r < 4; r++) {
            float p = __builtin_amdgcn_exp2f(fmaf(s[r], C1, -C2));
            if (diag && (quad * 4 + r > col)) p = 0.f;
            ps += p;
            pf8[mq][st * 4 + r] = (f16)p;
          }
          lsum[mq] += ps;
        }
      }
#pragma unroll
      for (int mq = 0; mq < 2; mq++)
#pragma unroll
        for (int sub = 0; sub < 4; sub++)
          o[mq][sub] = mfma_pv32(vvr[sub], pf8[mq], o[mq][sub]);
      __builtin_amdgcn_s_setprio(0);
    }
    __syncthreads();  // all waves done reading kv[buf]; stage(kt+1) landed
    buf ^= 1;
  }

#pragma unroll
  for (int mq = 0; mq < 2; mq++) {
    lsum[mq] += __shfl_xor(lsum[mq], 16);
    lsum[mq] += __shfl_xor(lsum[mq], 32);
    const float rinv = 1.f / lsum[mq];
    const int qrow = qbase + mq * 16 + col;
#pragma unroll
    for (int sub = 0; sub < 4; sub++) {
      bf16x4 yv;
#pragma unroll
      for (int r = 0; r < 4; r++) yv[r] = (bf16)(o[mq][sub][r] * rinv);
      *(bf16x4*)&Y[((size_t)b * T_ + qrow) * C_ + h * 64 + sub * 16 + quad * 4] = yv;
    }
  }
}

extern "C" void kernel_launch(void* const* d_in, const int* in_sizes, int n_in,
                              void* d_out, int out_size, void* d_ws, size_t ws_size,
                              hipStream_t stream) {
  (void)in_sizes; (void)n_in; (void)out_size; (void)ws_size;
  const float* x      = (const float*)d_in[0];  // [B*T, C]
  const float* w_qkv  = (const float*)d_in[1];  // [C, 3C]
  const float* b_qkv  = (const float*)d_in[2];  // [3C]
  const float* w_proj = (const float*)d_in[3];  // [C, C]
  const float* b_proj = (const float*)d_in[4];  // [C]

  char* ws = (char*)d_ws;
  bf16* wqkv_t  = (bf16*)(ws);                  // [3C, C]   6291456 B
  bf16* wproj_t = (bf16*)(ws + 6291456);        // [C, C]    2097152 B
  bf16* qb      = (bf16*)(ws + 8388608);        // [B,H,T,D] 16777216 B
  bf16* kbuf    = (bf16*)(ws + 25165824);       // K frag-major 16777216 B
  f16*  vtbuf   = (f16*)(ws + 41943040);        // V frag-major 16777216 B
  bf16* yb      = (bf16*)(ws + 58720256);       // [B*T, C]  16777216 B
  bf16* xb      = (bf16*)(ws + 58720256);       // aliases yb (dead before attn)

  preproc<<<12288, 256, 0, stream>>>(x, xb, w_qkv, wqkv_t, w_proj, wproj_t);
  // SWAPPED: A = wqkv_t (channels), Bt = xb (tokens)
  gemm128<0><<<dim3(64, 24), 256, 0, stream>>>(wqkv_t, xb, b_qkv, qb, kbuf, vtbuf,
                                               3072, 8192, 1024);
  attn<<<dim3(1024), 256, 0, stream>>>(qb, kbuf, vtbuf, yb);
  gemm128<1><<<dim3(8, 64), 256, 0, stream>>>(yb, wproj_t, b_proj, d_out, nullptr,
                                              nullptr, 8192, 1024, 1024);
}